// Round 4
// baseline (336.856 us; speedup 1.0000x reference)
//
#include <hip/hip_runtime.h>
#include <stdint.h>

#define TPE 4096
#define DM 512
#define HID 1408
#define NE 8

#define N4X   4194304   // 32768*512/4
#define N4W12 2883584   // 8*2816*512/4
#define N4W3  1441792   // 8*512*1408/4

typedef unsigned short u16;
typedef __attribute__((ext_vector_type(8))) __bf16 bf16x8;
typedef __attribute__((ext_vector_type(4))) float f32x4;

__device__ __forceinline__ u16 f2bf(float f) {
  union { float f; uint32_t u; } v; v.f = f;
  uint32_t u = v.u;
  u += 0x7fffu + ((u >> 16) & 1u);   // round-to-nearest-even
  return (u16)(u >> 16);
}

// ---------------- fused f32 -> bf16 convert for x, w12, w3 -----------------
__global__ void cvt_all(const float* __restrict__ x, const float* __restrict__ w12,
                        const float* __restrict__ w3, u16* __restrict__ xb,
                        u16* __restrict__ w12b, u16* __restrict__ w3b) {
  int i = blockIdx.x * blockDim.x + threadIdx.x;   // float4 index
  const float* src; u16* dst; int off;
  if (i < N4X)               { src = x;   dst = xb;   off = i; }
  else if (i < N4X + N4W12)  { src = w12; dst = w12b; off = i - N4X; }
  else                       { src = w3;  dst = w3b;  off = i - N4X - N4W12; }
  float4 v = reinterpret_cast<const float4*>(src)[off];
  union { u16 s[4]; uint2 u2; } o;
  o.s[0] = f2bf(v.x); o.s[1] = f2bf(v.y); o.s[2] = f2bf(v.z); o.s[3] = f2bf(v.w);
  reinterpret_cast<uint2*>(dst)[off] = o.u2;
}

// ------------- global->LDS async stage, ROWS x 64 bf16 tile ----------------
// Row = 128 B. XOR swizzle at 16B-chunk granularity: global chunk c of row r
// lands at LDS chunk c^(r&7) -> b128 reads are 2-way aliased (free, m136).
template <int ROWS>
__device__ __forceinline__ void stage_tile64(u16* lds, const u16* g, int lda,
                                             int wave, int lane) {
  const int srow = lane >> 3;                 // 0..7 within 8-row window
  const int gchunk = (lane & 7) ^ srow;       // schunk ^ (grow & 7)
#pragma unroll
  for (int r = 0; r < ROWS / 32; ++r) {
    const int row0 = (wave * (ROWS / 32) + r) * 8;
    const u16* gp = g + (size_t)(row0 + srow) * lda + gchunk * 8;
    u16* lp = lds + row0 * 64;                // 64 u16 (=128B) per row
    __builtin_amdgcn_global_load_lds((const __attribute__((address_space(1))) void*)gp,
                                     (__attribute__((address_space(3))) void*)lp,
                                     16, 0, 0);
  }
}

__device__ __forceinline__ bf16x8 read_frag(const u16* lds, int row, int kchunk) {
  return *reinterpret_cast<const bf16x8*>(&lds[row * 64 + (((kchunk ^ (row & 7)) << 3))]);
}

// ---------------- GEMM1 + fused SwiGLU (split into two mt-half dispatches) -
__global__ __launch_bounds__(256, 2)
void gemm1_swiglu(const u16* __restrict__ xb, const u16* __restrict__ w12b,
                  u16* __restrict__ hb, int mt0) {
  __shared__ u16 sA[128 * 64];
  __shared__ u16 sBg[128 * 64];
  __shared__ u16 sBu[128 * 64];
  const int mt = blockIdx.x + mt0, nt = blockIdx.y, e = blockIdx.z;
  const int tid = threadIdx.x, wave = tid >> 6, lane = tid & 63;
  const int wm = wave >> 1, wn = wave & 1;
  const int quad = lane >> 4, rr = lane & 15;

  const u16* A  = xb + (size_t)(e * TPE + mt * 128) * DM;
  const u16* Bg = w12b + (size_t)e * (2 * HID) * DM + (size_t)(nt * 128) * DM;
  const u16* Bu = Bg + (size_t)HID * DM;

  f32x4 zero = {0.f, 0.f, 0.f, 0.f};
  f32x4 accg[4][4], accu[4][4];
#pragma unroll
  for (int i = 0; i < 4; ++i)
#pragma unroll
    for (int j = 0; j < 4; ++j) { accg[i][j] = zero; accu[i][j] = zero; }

  for (int k0 = 0; k0 < DM; k0 += 64) {
    stage_tile64<128>(sA, A + k0, DM, wave, lane);
    stage_tile64<128>(sBg, Bg + k0, DM, wave, lane);
    stage_tile64<128>(sBu, Bu + k0, DM, wave, lane);
    __syncthreads();

#pragma unroll
    for (int kk = 0; kk < 2; ++kk) {
      const int kc = kk * 4 + quad;
      bf16x8 af[4], bg[4], bu[4];
#pragma unroll
      for (int mi = 0; mi < 4; ++mi)
        af[mi] = read_frag(sA, wm * 64 + mi * 16 + rr, kc);
#pragma unroll
      for (int ni = 0; ni < 4; ++ni) {
        bg[ni] = read_frag(sBg, wn * 64 + ni * 16 + rr, kc);
        bu[ni] = read_frag(sBu, wn * 64 + ni * 16 + rr, kc);
      }
#pragma unroll
      for (int mi = 0; mi < 4; ++mi)
#pragma unroll
        for (int ni = 0; ni < 4; ++ni) {
          accg[mi][ni] = __builtin_amdgcn_mfma_f32_16x16x32_bf16(af[mi], bg[ni], accg[mi][ni], 0, 0, 0);
          accu[mi][ni] = __builtin_amdgcn_mfma_f32_16x16x32_bf16(af[mi], bu[ni], accu[mi][ni], 0, 0, 0);
        }
    }
    __syncthreads();
  }

  const size_t rowbase = (size_t)(e * TPE + mt * 128 + wm * 64);
  const int colbase = nt * 128 + wn * 64;
#pragma unroll
  for (int mi = 0; mi < 4; ++mi)
#pragma unroll
    for (int ni = 0; ni < 4; ++ni)
#pragma unroll
      for (int r2 = 0; r2 < 4; ++r2) {
        float g = accg[mi][ni][r2];
        float u = accu[mi][ni][r2];
        float s = (g / (1.f + __expf(-g))) * u;
        size_t row = rowbase + mi * 16 + quad * 4 + r2;
        int col = colbase + ni * 16 + rr;
        hb[row * HID + col] = f2bf(s);
      }
}

// ---------------- GEMM2: h @ w3^T -> out (f32), 128x128 tiles --------------
// m112: 128-square is the tile sweet spot. Grid (32,4,8)=1024 = 4/CU,
// LDS 24 KB -> up to 6 resident.
__global__ __launch_bounds__(256, 2)
void gemm2(const u16* __restrict__ hb, const u16* __restrict__ w3b,
           float* __restrict__ out) {
  __shared__ u16 sA[128 * 64];
  __shared__ u16 sB[128 * 64];
  const int mt = blockIdx.x, nt = blockIdx.y, e = blockIdx.z;
  const int tid = threadIdx.x, wave = tid >> 6, lane = tid & 63;
  const int wm = wave >> 1, wn = wave & 1;
  const int quad = lane >> 4, rr = lane & 15;

  const u16* A = hb + (size_t)(e * TPE + mt * 128) * HID;
  const u16* B = w3b + (size_t)e * DM * HID + (size_t)(nt * 128) * HID;

  f32x4 zero = {0.f, 0.f, 0.f, 0.f};
  f32x4 acc[4][4];
#pragma unroll
  for (int i = 0; i < 4; ++i)
#pragma unroll
    for (int j = 0; j < 4; ++j) acc[i][j] = zero;

  for (int k0 = 0; k0 < HID; k0 += 64) {
    stage_tile64<128>(sA, A + k0, HID, wave, lane);
    stage_tile64<128>(sB, B + k0, HID, wave, lane);
    __syncthreads();

#pragma unroll
    for (int kk = 0; kk < 2; ++kk) {
      const int kc = kk * 4 + quad;
      bf16x8 af[4], bfr[4];
#pragma unroll
      for (int mi = 0; mi < 4; ++mi)
        af[mi] = read_frag(sA, wm * 64 + mi * 16 + rr, kc);
#pragma unroll
      for (int ni = 0; ni < 4; ++ni)
        bfr[ni] = read_frag(sB, wn * 64 + ni * 16 + rr, kc);
#pragma unroll
      for (int mi = 0; mi < 4; ++mi)
#pragma unroll
        for (int ni = 0; ni < 4; ++ni)
          acc[mi][ni] = __builtin_amdgcn_mfma_f32_16x16x32_bf16(af[mi], bfr[ni], acc[mi][ni], 0, 0, 0);
    }
    __syncthreads();
  }

  const size_t rowbase = (size_t)(e * TPE + mt * 128 + wm * 64);
  const int colbase = nt * 128 + wn * 64;
#pragma unroll
  for (int mi = 0; mi < 4; ++mi)
#pragma unroll
    for (int ni = 0; ni < 4; ++ni)
#pragma unroll
      for (int r2 = 0; r2 < 4; ++r2) {
        size_t row = rowbase + mi * 16 + quad * 4 + r2;
        int col = colbase + ni * 16 + rr;
        out[row * DM + col] = acc[mi][ni][r2];
      }
}

// ---------------------------------------------------------------------------
extern "C" void kernel_launch(void* const* d_in, const int* in_sizes, int n_in,
                              void* d_out, int out_size, void* d_ws, size_t ws_size,
                              hipStream_t stream) {
  (void)in_sizes; (void)n_in; (void)out_size; (void)ws_size;
  const float* x   = (const float*)d_in[0];
  const float* w12 = (const float*)d_in[1];
  const float* w3  = (const float*)d_in[2];
  float* out = (float*)d_out;

  char* ws = (char*)d_ws;
  u16* xb   = (u16*)(ws);
  u16* w12b = (u16*)(ws + (size_t)33554432);
  u16* w3b  = (u16*)(ws + (size_t)33554432 + 23068672);
  u16* hb   = (u16*)(ws + (size_t)33554432 + 23068672 + 11534336);

  const int n4 = N4X + N4W12 + N4W3;   // 8,519,680 -> 33280 blocks
  cvt_all<<<n4 / 256, 256, 0, stream>>>(x, w12, w3, xb, w12b, w3b);

  // gemm1 split into two mt-halves (diagnostic: lowers top-5 floor to ~56us
  // so the hidden gemm2/cvt durations surface with counters)
  gemm1_swiglu<<<dim3(16, 11, NE), 256, 0, stream>>>(xb, w12b, hb, 0);
  gemm1_swiglu<<<dim3(16, 11, NE), 256, 0, stream>>>(xb, w12b, hb, 16);

  gemm2<<<dim3(32, 4, NE), 256, 0, stream>>>(hb, w3b, out);
}

// Round 5
// 309.880 us; speedup vs baseline: 1.0871x; 1.0871x over previous
//
#include <hip/hip_runtime.h>
#include <stdint.h>

#define TPE 4096
#define DM 512
#define HID 1408
#define NE 8

#define N4X   4194304   // 32768*512/4
#define N4W12 2883584   // 8*2816*512/4
#define N4W3  1441792   // 8*512*1408/4  = 352*4096

typedef unsigned short u16;
typedef __attribute__((ext_vector_type(8))) __bf16 bf16x8;
typedef __attribute__((ext_vector_type(4))) float f32x4;

__device__ __forceinline__ u16 f2bf(float f) {
  union { float f; uint32_t u; } v; v.f = f;
  uint32_t u = v.u;
  u += 0x7fffu + ((u >> 16) & 1u);   // round-to-nearest-even
  return (u16)(u >> 16);
}

// ---------------- f32 -> bf16 convert for x and w12 only -------------------
__global__ void cvt_xw12(const float* __restrict__ x, const float* __restrict__ w12,
                         u16* __restrict__ xb, u16* __restrict__ w12b) {
  int i = blockIdx.x * blockDim.x + threadIdx.x;   // float4 index
  const float* src; u16* dst; int off;
  if (i < N4X) { src = x;   dst = xb;   off = i; }
  else         { src = w12; dst = w12b; off = i - N4X; }
  float4 v = reinterpret_cast<const float4*>(src)[off];
  union { u16 s[4]; uint2 u2; } o;
  o.s[0] = f2bf(v.x); o.s[1] = f2bf(v.y); o.s[2] = f2bf(v.z); o.s[3] = f2bf(v.w);
  reinterpret_cast<uint2*>(dst)[off] = o.u2;
}

// ------------- global->LDS async stage, ROWS x 64 bf16 tile ----------------
// Row = 128 B. XOR swizzle at 16B-chunk granularity: global chunk c of row r
// lands at LDS chunk c^(r&7) -> b128 reads are 2-way aliased (free, m136).
template <int ROWS>
__device__ __forceinline__ void stage_tile64(u16* lds, const u16* g, int lda,
                                             int wave, int lane) {
  const int srow = lane >> 3;                 // 0..7 within 8-row window
  const int gchunk = (lane & 7) ^ srow;       // schunk ^ (grow & 7)
#pragma unroll
  for (int r = 0; r < ROWS / 32; ++r) {
    const int row0 = (wave * (ROWS / 32) + r) * 8;
    const u16* gp = g + (size_t)(row0 + srow) * lda + gchunk * 8;
    u16* lp = lds + row0 * 64;                // 64 u16 (=128B) per row
    __builtin_amdgcn_global_load_lds((const __attribute__((address_space(1))) void*)gp,
                                     (__attribute__((address_space(3))) void*)lp,
                                     16, 0, 0);
  }
}

__device__ __forceinline__ bf16x8 read_frag(const u16* lds, int row, int kchunk) {
  return *reinterpret_cast<const bf16x8*>(&lds[row * 64 + (((kchunk ^ (row & 7)) << 3))]);
}

// ---------------- GEMM1 + fused SwiGLU, XCD-pinned per expert --------------
// grid (8, 352+44): blockIdx.x = e -> with flat%8 XCD round-robin, expert e's
// blocks all land on XCD e, so w12_e (2.9 MB bf16) stays L2-resident.
// y = mt*11 + nt (nt fastest) -> each A-tile reused 11x while L2-hot.
// y in [352,396): tail blocks convert w3 f32->bf16 (hidden under GEMM).
__global__ __launch_bounds__(256, 2)
void gemm1_swiglu(const u16* __restrict__ xb, const u16* __restrict__ w12b,
                  u16* __restrict__ hb, const float* __restrict__ w3f,
                  u16* __restrict__ w3b) {
  __shared__ u16 sA[128 * 64];
  __shared__ u16 sBg[128 * 64];
  __shared__ u16 sBu[128 * 64];
  const int e = blockIdx.x;
  const int y = blockIdx.y;
  const int tid = threadIdx.x;

  if (y >= 352) {   // w3 conversion tail: 352 blocks x 4096 float4
    const int c = e + 8 * (y - 352);          // 0..351
    const float4* src = reinterpret_cast<const float4*>(w3f) + (size_t)c * 4096;
    uint2* dst = reinterpret_cast<uint2*>(w3b) + (size_t)c * 4096;
#pragma unroll
    for (int it = 0; it < 16; ++it) {
      float4 v = src[it * 256 + tid];
      union { u16 s[4]; uint2 u2; } o;
      o.s[0] = f2bf(v.x); o.s[1] = f2bf(v.y); o.s[2] = f2bf(v.z); o.s[3] = f2bf(v.w);
      dst[it * 256 + tid] = o.u2;
    }
    return;
  }

  const int mt = y / 11, nt = y % 11;
  const int wave = tid >> 6, lane = tid & 63;
  const int wm = wave >> 1, wn = wave & 1;
  const int quad = lane >> 4, rr = lane & 15;

  const u16* A  = xb + (size_t)(e * TPE + mt * 128) * DM;
  const u16* Bg = w12b + (size_t)e * (2 * HID) * DM + (size_t)(nt * 128) * DM;
  const u16* Bu = Bg + (size_t)HID * DM;

  f32x4 zero = {0.f, 0.f, 0.f, 0.f};
  f32x4 accg[4][4], accu[4][4];
#pragma unroll
  for (int i = 0; i < 4; ++i)
#pragma unroll
    for (int j = 0; j < 4; ++j) { accg[i][j] = zero; accu[i][j] = zero; }

  for (int k0 = 0; k0 < DM; k0 += 64) {
    stage_tile64<128>(sA, A + k0, DM, wave, lane);
    stage_tile64<128>(sBg, Bg + k0, DM, wave, lane);
    stage_tile64<128>(sBu, Bu + k0, DM, wave, lane);
    __syncthreads();

#pragma unroll
    for (int kk = 0; kk < 2; ++kk) {
      const int kc = kk * 4 + quad;
      bf16x8 af[4], bg[4], bu[4];
#pragma unroll
      for (int mi = 0; mi < 4; ++mi)
        af[mi] = read_frag(sA, wm * 64 + mi * 16 + rr, kc);
#pragma unroll
      for (int ni = 0; ni < 4; ++ni) {
        bg[ni] = read_frag(sBg, wn * 64 + ni * 16 + rr, kc);
        bu[ni] = read_frag(sBu, wn * 64 + ni * 16 + rr, kc);
      }
#pragma unroll
      for (int mi = 0; mi < 4; ++mi)
#pragma unroll
        for (int ni = 0; ni < 4; ++ni) {
          accg[mi][ni] = __builtin_amdgcn_mfma_f32_16x16x32_bf16(af[mi], bg[ni], accg[mi][ni], 0, 0, 0);
          accu[mi][ni] = __builtin_amdgcn_mfma_f32_16x16x32_bf16(af[mi], bu[ni], accu[mi][ni], 0, 0, 0);
        }
    }
    __syncthreads();
  }

  const size_t rowbase = (size_t)(e * TPE + mt * 128 + wm * 64);
  const int colbase = nt * 128 + wn * 64;
#pragma unroll
  for (int mi = 0; mi < 4; ++mi)
#pragma unroll
    for (int ni = 0; ni < 4; ++ni)
#pragma unroll
      for (int r2 = 0; r2 < 4; ++r2) {
        float g = accg[mi][ni][r2];
        float u = accu[mi][ni][r2];
        float s = (g / (1.f + __expf(-g))) * u;
        size_t row = rowbase + mi * 16 + quad * 4 + r2;
        int col = colbase + ni * 16 + rr;
        hb[row * HID + col] = f2bf(s);
      }
}

// ---------------- GEMM2: h @ w3^T -> out (f32), 128x256, XCD-pinned --------
// grid (8, 64): x = e -> XCD pin (w3_e 1.4 MB L2-resident); y = mt*2 + nt.
__global__ __launch_bounds__(256, 2)
void gemm2(const u16* __restrict__ hb, const u16* __restrict__ w3b,
           float* __restrict__ out) {
  __shared__ u16 sA[128 * 64];
  __shared__ u16 sB[256 * 64];
  const int e = blockIdx.x;
  const int mt = blockIdx.y >> 1, nt = blockIdx.y & 1;
  const int tid = threadIdx.x, wave = tid >> 6, lane = tid & 63;
  const int wm = wave >> 1, wn = wave & 1;
  const int quad = lane >> 4, rr = lane & 15;

  const u16* A = hb + (size_t)(e * TPE + mt * 128) * HID;
  const u16* B = w3b + (size_t)e * DM * HID + (size_t)(nt * 256) * HID;

  f32x4 zero = {0.f, 0.f, 0.f, 0.f};
  f32x4 acc[4][8];
#pragma unroll
  for (int i = 0; i < 4; ++i)
#pragma unroll
    for (int j = 0; j < 8; ++j) acc[i][j] = zero;

  for (int k0 = 0; k0 < HID; k0 += 64) {
    stage_tile64<128>(sA, A + k0, HID, wave, lane);
    stage_tile64<256>(sB, B + k0, HID, wave, lane);
    __syncthreads();

#pragma unroll
    for (int kk = 0; kk < 2; ++kk) {
      const int kc = kk * 4 + quad;
      bf16x8 af[4], bfr[8];
#pragma unroll
      for (int mi = 0; mi < 4; ++mi)
        af[mi] = read_frag(sA, wm * 64 + mi * 16 + rr, kc);
#pragma unroll
      for (int ni = 0; ni < 8; ++ni)
        bfr[ni] = read_frag(sB, wn * 128 + ni * 16 + rr, kc);
#pragma unroll
      for (int mi = 0; mi < 4; ++mi)
#pragma unroll
        for (int ni = 0; ni < 8; ++ni)
          acc[mi][ni] = __builtin_amdgcn_mfma_f32_16x16x32_bf16(af[mi], bfr[ni], acc[mi][ni], 0, 0, 0);
    }
    __syncthreads();
  }

  const size_t rowbase = (size_t)(e * TPE + mt * 128 + wm * 64);
  const int colbase = nt * 256 + wn * 128;
#pragma unroll
  for (int mi = 0; mi < 4; ++mi)
#pragma unroll
    for (int ni = 0; ni < 8; ++ni)
#pragma unroll
      for (int r2 = 0; r2 < 4; ++r2) {
        size_t row = rowbase + mi * 16 + quad * 4 + r2;
        int col = colbase + ni * 16 + rr;
        out[row * DM + col] = acc[mi][ni][r2];
      }
}

// ---------------------------------------------------------------------------
extern "C" void kernel_launch(void* const* d_in, const int* in_sizes, int n_in,
                              void* d_out, int out_size, void* d_ws, size_t ws_size,
                              hipStream_t stream) {
  (void)in_sizes; (void)n_in; (void)out_size; (void)ws_size;
  const float* x   = (const float*)d_in[0];
  const float* w12 = (const float*)d_in[1];
  const float* w3  = (const float*)d_in[2];
  float* out = (float*)d_out;

  char* ws = (char*)d_ws;
  u16* xb   = (u16*)(ws);
  u16* w12b = (u16*)(ws + (size_t)33554432);
  u16* w3b  = (u16*)(ws + (size_t)33554432 + 23068672);
  u16* hb   = (u16*)(ws + (size_t)33554432 + 23068672 + 11534336);

  const int n4 = N4X + N4W12;   // 7,077,888 -> 27648 blocks
  cvt_xw12<<<n4 / 256, 256, 0, stream>>>(x, w12, xb, w12b);

  // gemm1: XCD-pinned (x=e); y = mt*11+nt for tiles, y>=352 converts w3
  gemm1_swiglu<<<dim3(8, 352 + 44), 256, 0, stream>>>(xb, w12b, hb, w3, w3b);
  gemm2<<<dim3(8, 64), 256, 0, stream>>>(hb, w3b, out);
}